// Round 2
// baseline (20193.950 us; speedup 1.0000x reference)
//
#include <hip/hip_runtime.h>

// LSTM T=2048, B=32, E=512, H=512 (fp32 in/out).
// R1: flag-free recurrence. 4-deep h ring in L3; consumers poll poison-tagged
// 8B data chunks directly (one L3 round trip per step). No __syncthreads in
// the loop; Wh fragments live in VGPRs; h slice published as one atomic u64.

#define T_STEPS 2048
#define BATCH   32
#define EDIM    512
#define HDIM    512
#define NW      128   // recurrent workgroups, each owns 4 h-columns
#define NJ      4
#define NCOL    16    // 4 gates * NJ packed columns per WG
#define WG_THREADS 128
#define BSTRIDE 1032
#define DEPTH   4
#define BUF64   ((BATCH * HDIM) / 4)   // u64 words per h buffer = 4096
#define ROW64   (HDIM / 4)             // u64 words per batch row = 128
#define POISON  0xFFFFFFFFFFFFFFFFull

typedef unsigned int       u32;
typedef unsigned long long u64;
typedef unsigned short     u16;
typedef float  floatx4 __attribute__((ext_vector_type(4)));
typedef __bf16 bf16x8  __attribute__((ext_vector_type(8)));

union BF16U { __bf16 b; u16 u; };
__device__ __forceinline__ u16 f2bf(float f) { BF16U x; x.b = (__bf16)f; return x.u; }

__device__ __forceinline__ float fast_sigmoid(float x) {
  return 1.0f / (1.0f + __expf(-x));
}
__device__ __forceinline__ float fast_tanh(float x) {
  float e = __expf(-2.0f * fabsf(x));
  float t = (1.0f - e) / (1.0f + e);
  return x >= 0.0f ? t : -t;
}

// ---------------------------------------------------------------- phase 1
__global__ void lstm_prep(const float* __restrict__ emb, u16* __restrict__ embb,
                          const float* __restrict__ h0, u64* __restrict__ hb) {
  const size_t n4 = (size_t)T_STEPS * BATCH * EDIM / 4;
  size_t stride = (size_t)gridDim.x * blockDim.x;
  size_t gid = (size_t)blockIdx.x * blockDim.x + threadIdx.x;
  for (size_t i = gid; i < n4; i += stride) {
    float4 v = ((const float4*)emb)[i];
    ushort4 o;
    o.x = f2bf(v.x); o.y = f2bf(v.y); o.z = f2bf(v.z); o.w = f2bf(v.w);
    ((ushort4*)embb)[i] = o;
  }
  // buf[0] = bf16(h_0)  (sanitize any accidental poison pattern)
  if (gid < (size_t)BATCH * HDIM) {
    u16 v = f2bf(h0[gid]);
    if (v == 0xFFFFu) v = 0xFFC0u;
    ((u16*)hb)[gid] = v;
  }
  // poison buf[1..3]
  if (gid < 3 * (size_t)BUF64) hb[BUF64 + gid] = POISON;
}

// ---------------------------------------------------------------- phase 2
__global__ void __launch_bounds__(WG_THREADS, 1)
lstm_rec(const u16* __restrict__ embb,
         const float* __restrict__ c0,
         const float* __restrict__ Wx0, const float* __restrict__ Wh0, const float* __restrict__ b0,
         const float* __restrict__ Wx1, const float* __restrict__ Wh1, const float* __restrict__ b1,
         const float* __restrict__ Wx2, const float* __restrict__ Wh2, const float* __restrict__ b2,
         const float* __restrict__ Wx3, const float* __restrict__ Wh3, const float* __restrict__ b3,
         u64* __restrict__ hb,              // [DEPTH][BUF64] u64 (bf16 h ring)
         float* __restrict__ out) {
  __shared__ __align__(16) __bf16 Blds[NCOL][BSTRIDE];   // [packed col][k], bf16
  __shared__ float gbuf[BATCH][NCOL + 1];                // fp32 pre-activations
  __shared__ __align__(8) u16 hstage[BATCH][4];          // h slice staging

  const int tid    = threadIdx.x;
  const int w      = blockIdx.x;
  const int j0     = w * NJ;
  const int lane   = tid & 63;
  const int waveid = tid >> 6;          // 0..1 = batch half
  const int nlo    = lane & 15;
  const int q      = lane >> 4;
  const int mrow   = waveid * 16 + nlo;

  const float* Wx[4] = {Wx0, Wx1, Wx2, Wx3};
  const float* Wh[4] = {Wh0, Wh1, Wh2, Wh3};

  // ---- stage [Wx;Wh] slice into LDS as bf16
  for (int g = 0; g < 4; ++g) {
    for (int base = 0; base < EDIM; base += WG_THREADS) {
      int kk = base + tid;
      float4 wx = *(const float4*)(Wx[g] + (size_t)kk * HDIM + j0);
      float4 wh = *(const float4*)(Wh[g] + (size_t)kk * HDIM + j0);
      Blds[g*NJ+0][kk] = (__bf16)wx.x;  Blds[g*NJ+0][EDIM+kk] = (__bf16)wh.x;
      Blds[g*NJ+1][kk] = (__bf16)wx.y;  Blds[g*NJ+1][EDIM+kk] = (__bf16)wh.y;
      Blds[g*NJ+2][kk] = (__bf16)wx.z;  Blds[g*NJ+2][EDIM+kk] = (__bf16)wh.z;
      Blds[g*NJ+3][kk] = (__bf16)wx.w;  Blds[g*NJ+3][EDIM+kk] = (__bf16)wh.w;
    }
  }

  // ---- epilogue state: thread -> (batch eb, column ej); eb stays in own wave
  const int eb = tid >> 2;        // wave0: 0..15, wave1: 16..31
  const int ej = tid & 3;
  const int jg = j0 + ej;
  float cst = c0[(size_t)eb * HDIM + jg];
  const float bgv = b0[jg], biv = b1[jg], bfv = b2[jg], bov = b3[jg];

  __syncthreads();   // staging complete (only barrier in the kernel)

  // ---- preload Wh fragments into registers (64 VGPRs)
  bf16x8 bhf[16];
#pragma unroll
  for (int s = 0; s < 16; ++s)
    bhf[s] = *reinterpret_cast<const bf16x8*>(&Blds[nlo][EDIM + s * 32 + q * 8]);

  const int  myrow = waveid * 16 + lane;   // rows this wave publishes (lane<16)
  const bool hpub  = (lane < 16);

  for (int t = 0; t < T_STEPS; ++t) {
    // ---- poison own chunk of buf[(t+2)%4] (safe: everyone finished iter t-2;
    //      drained by the vmcnt(0) before this iter's publish)
    if (hpub)
      __hip_atomic_store(&hb[(size_t)((t + 2) & 3) * BUF64 + (size_t)myrow * ROW64 + w],
                         POISON, __ATOMIC_RELAXED, __HIP_MEMORY_SCOPE_AGENT);

    // ---- issue all h-chunk loads early (latency hides under emb MFMA block)
    const u64* hrow = hb + (size_t)(t & 3) * BUF64 + (size_t)mrow * ROW64;
    u64 hva[16], hvb[16];
#pragma unroll
    for (int s = 0; s < 16; ++s) {
      hva[s] = __hip_atomic_load(&hrow[8*s + 2*q],     __ATOMIC_RELAXED, __HIP_MEMORY_SCOPE_AGENT);
      hvb[s] = __hip_atomic_load(&hrow[8*s + 2*q + 1], __ATOMIC_RELAXED, __HIP_MEMORY_SCOPE_AGENT);
    }

    // ---- emb part (independent of recurrence)
    floatx4 acc0 = {0.f, 0.f, 0.f, 0.f};
    floatx4 acc1 = {0.f, 0.f, 0.f, 0.f};
    const u16* erow = embb + ((size_t)t * BATCH + mrow) * EDIM;
#pragma unroll
    for (int s = 0; s < 16; s += 2) {
      int k0 = s * 32 + q * 8;
      int k1 = (s + 1) * 32 + q * 8;
      bf16x8 a0 = *reinterpret_cast<const bf16x8*>(erow + k0);
      bf16x8 a1 = *reinterpret_cast<const bf16x8*>(erow + k1);
      bf16x8 w0 = *reinterpret_cast<const bf16x8*>(&Blds[nlo][k0]);
      bf16x8 w1 = *reinterpret_cast<const bf16x8*>(&Blds[nlo][k1]);
      acc0 = __builtin_amdgcn_mfma_f32_16x16x32_bf16(a0, w0, acc0, 0, 0, 0);
      acc1 = __builtin_amdgcn_mfma_f32_16x16x32_bf16(a1, w1, acc1, 0, 0, 0);
    }

    // ---- h part: per-chunk poison poll, then MFMA with register Wh frags
#pragma unroll
    for (int s = 0; s < 16; ++s) {
      u64 a = hva[s], b = hvb[s];
      while (!__all((a != POISON) && (b != POISON))) {
        a = __hip_atomic_load(&hrow[8*s + 2*q],     __ATOMIC_RELAXED, __HIP_MEMORY_SCOPE_AGENT);
        b = __hip_atomic_load(&hrow[8*s + 2*q + 1], __ATOMIC_RELAXED, __HIP_MEMORY_SCOPE_AGENT);
      }
      union { u64 qv[2]; bf16x8 v; } ua;
      ua.qv[0] = a; ua.qv[1] = b;
      if (s & 1) acc1 = __builtin_amdgcn_mfma_f32_16x16x32_bf16(ua.v, bhf[s], acc1, 0, 0, 0);
      else       acc0 = __builtin_amdgcn_mfma_f32_16x16x32_bf16(ua.v, bhf[s], acc0, 0, 0, 0);
    }

    // ---- stage pre-activations (wave-local rows; in-order DS, no barrier)
#pragma unroll
    for (int r = 0; r < 4; ++r)
      gbuf[waveid * 16 + q * 4 + r][nlo] = acc0[r] + acc1[r];

    // ---- epilogue (reads only own wave's gbuf rows)
    float gv = fast_tanh   (gbuf[eb][ej]      + bgv);
    float iv = fast_sigmoid(gbuf[eb][4 + ej]  + biv);
    float fv = fast_sigmoid(gbuf[eb][8 + ej]  + bfv);
    float ov = fast_sigmoid(gbuf[eb][12 + ej] + bov);
    cst = gv * iv + cst * fv;
    float hv = fast_tanh(cst) * ov;

    hstage[eb][ej] = f2bf(hv);   // wave-local rows

    // ---- publish h slice: one atomic u64 per row (lanes 0..15 of each wave)
    if (hpub) {
      u64 hword = *reinterpret_cast<const u64*>(&hstage[myrow][0]);
      // orders this iter's poison (issued ~1 full chunk of work ago) before
      // the publish; poll loads all returned, so the wait is ~free
      asm volatile("s_waitcnt vmcnt(0)" ::: "memory");
      __hip_atomic_store(&hb[(size_t)((t + 1) & 3) * BUF64 + (size_t)myrow * ROW64 + w],
                         hword, __ATOMIC_RELAXED, __HIP_MEMORY_SCOPE_AGENT);
    }

    // ---- seq output (after publish so its ack is off the critical path)
    out[((size_t)t * BATCH + eb) * HDIM + jg] = hv;
    if (t == T_STEPS - 1) {
      const size_t seqN = (size_t)T_STEPS * BATCH * HDIM;
      out[seqN + (size_t)eb * HDIM + jg] = hv;
      out[seqN + (size_t)BATCH * HDIM + (size_t)eb * HDIM + jg] = cst;
    }
  }
}

// ---------------------------------------------------------------- launch
extern "C" void kernel_launch(void* const* d_in, const int* in_sizes, int n_in,
                              void* d_out, int out_size, void* d_ws, size_t ws_size,
                              hipStream_t stream) {
  const float* emb = (const float*)d_in[0];
  const float* h0  = (const float*)d_in[1];
  const float* c0  = (const float*)d_in[2];
  const float* Wgx = (const float*)d_in[3];
  const float* Wgh = (const float*)d_in[4];
  const float* bg  = (const float*)d_in[5];
  const float* Wix = (const float*)d_in[6];
  const float* Wih = (const float*)d_in[7];
  const float* bi  = (const float*)d_in[8];
  const float* Wfx = (const float*)d_in[9];
  const float* Wfh = (const float*)d_in[10];
  const float* bf  = (const float*)d_in[11];
  const float* Wox = (const float*)d_in[12];
  const float* Woh = (const float*)d_in[13];
  const float* bo  = (const float*)d_in[14];
  float* out = (float*)d_out;

  char* ws = (char*)d_ws;
  const size_t embb_bytes = (size_t)T_STEPS * BATCH * EDIM * 2;   // 64 MiB
  u16* embb = (u16*)ws;
  u64* hb   = (u64*)(ws + embb_bytes);                            // 128 KiB ring

  lstm_prep<<<4096, 256, 0, stream>>>(emb, embb, h0, hb);
  lstm_rec<<<NW, WG_THREADS, 0, stream>>>(embb, c0,
                                          Wgx, Wgh, bg,
                                          Wix, Wih, bi,
                                          Wfx, Wfh, bf,
                                          Wox, Woh, bo,
                                          hb, out);
}

// Round 3
// 17492.026 us; speedup vs baseline: 1.1545x; 1.1545x over previous
//
#include <hip/hip_runtime.h>

// LSTM T=2048, B=32, E=512, H=512 (fp32 in/out).
// R2: poison-tagged 4-deep h ring polled with a BATCHED retry (R1's serial
// per-chunk retry cost ~16 L3 round trips per step; this costs 1-2).
// No barriers in the loop; Wh fragments in VGPRs; h published as atomic u64.

#define T_STEPS 2048
#define BATCH   32
#define EDIM    512
#define HDIM    512
#define NW      128   // recurrent workgroups, each owns 4 h-columns
#define NJ      4
#define NCOL    16    // 4 gates * NJ packed columns per WG
#define WG_THREADS 128
#define BSTRIDE 1032
#define DEPTH   4
#define BUF64   ((BATCH * HDIM) / 4)   // u64 words per h buffer = 4096
#define ROW64   (HDIM / 4)             // u64 words per batch row = 128
#define POISON  0xFFFFFFFFFFFFFFFFull

typedef unsigned int       u32;
typedef unsigned long long u64;
typedef unsigned short     u16;
typedef float  floatx4 __attribute__((ext_vector_type(4)));
typedef __bf16 bf16x8  __attribute__((ext_vector_type(8)));

union BF16U { __bf16 b; u16 u; };
__device__ __forceinline__ u16 f2bf(float f) { BF16U x; x.b = (__bf16)f; return x.u; }

__device__ __forceinline__ float fast_sigmoid(float x) {
  return 1.0f / (1.0f + __expf(-x));
}
__device__ __forceinline__ float fast_tanh(float x) {
  float e = __expf(-2.0f * fabsf(x));
  float t = (1.0f - e) / (1.0f + e);
  return x >= 0.0f ? t : -t;
}

// ---------------------------------------------------------------- phase 1
__global__ void lstm_prep(const float* __restrict__ emb, u16* __restrict__ embb,
                          const float* __restrict__ h0, u64* __restrict__ hb) {
  const size_t n4 = (size_t)T_STEPS * BATCH * EDIM / 4;
  size_t stride = (size_t)gridDim.x * blockDim.x;
  size_t gid = (size_t)blockIdx.x * blockDim.x + threadIdx.x;
  for (size_t i = gid; i < n4; i += stride) {
    float4 v = ((const float4*)emb)[i];
    ushort4 o;
    o.x = f2bf(v.x); o.y = f2bf(v.y); o.z = f2bf(v.z); o.w = f2bf(v.w);
    ((ushort4*)embb)[i] = o;
  }
  // buf[0] = bf16(h_0)  (sanitize any accidental poison pattern)
  if (gid < (size_t)BATCH * HDIM) {
    u16 v = f2bf(h0[gid]);
    if (v == 0xFFFFu) v = 0xFFC0u;
    ((u16*)hb)[gid] = v;
  }
  // poison buf[1..3]
  if (gid < 3 * (size_t)BUF64) hb[BUF64 + gid] = POISON;
}

// ---------------------------------------------------------------- phase 2
__global__ void __launch_bounds__(WG_THREADS, 1)
lstm_rec(const u16* __restrict__ embb,
         const float* __restrict__ c0,
         const float* __restrict__ Wx0, const float* __restrict__ Wh0, const float* __restrict__ b0,
         const float* __restrict__ Wx1, const float* __restrict__ Wh1, const float* __restrict__ b1,
         const float* __restrict__ Wx2, const float* __restrict__ Wh2, const float* __restrict__ b2,
         const float* __restrict__ Wx3, const float* __restrict__ Wh3, const float* __restrict__ b3,
         u64* __restrict__ hb,              // [DEPTH][BUF64] u64 (bf16 h ring)
         float* __restrict__ out) {
  __shared__ __align__(16) __bf16 Blds[NCOL][BSTRIDE];   // [packed col][k], bf16
  __shared__ float gbuf[BATCH][NCOL + 1];                // fp32 pre-activations
  __shared__ __align__(8) u16 hstage[BATCH][4];          // h slice staging

  const int tid    = threadIdx.x;
  const int w      = blockIdx.x;
  const int j0     = w * NJ;
  const int lane   = tid & 63;
  const int waveid = tid >> 6;          // 0..1 = batch half
  const int nlo    = lane & 15;
  const int q      = lane >> 4;
  const int mrow   = waveid * 16 + nlo;

  const float* Wx[4] = {Wx0, Wx1, Wx2, Wx3};
  const float* Wh[4] = {Wh0, Wh1, Wh2, Wh3};

  // ---- stage [Wx;Wh] slice into LDS as bf16
  for (int g = 0; g < 4; ++g) {
    for (int base = 0; base < EDIM; base += WG_THREADS) {
      int kk = base + tid;
      float4 wx = *(const float4*)(Wx[g] + (size_t)kk * HDIM + j0);
      float4 wh = *(const float4*)(Wh[g] + (size_t)kk * HDIM + j0);
      Blds[g*NJ+0][kk] = (__bf16)wx.x;  Blds[g*NJ+0][EDIM+kk] = (__bf16)wh.x;
      Blds[g*NJ+1][kk] = (__bf16)wx.y;  Blds[g*NJ+1][EDIM+kk] = (__bf16)wh.y;
      Blds[g*NJ+2][kk] = (__bf16)wx.z;  Blds[g*NJ+2][EDIM+kk] = (__bf16)wh.z;
      Blds[g*NJ+3][kk] = (__bf16)wx.w;  Blds[g*NJ+3][EDIM+kk] = (__bf16)wh.w;
    }
  }

  // ---- epilogue state: thread -> (batch eb, column ej); eb stays in own wave
  const int eb = tid >> 2;        // wave0: 0..15, wave1: 16..31
  const int ej = tid & 3;
  const int jg = j0 + ej;
  float cst = c0[(size_t)eb * HDIM + jg];
  const float bgv = b0[jg], biv = b1[jg], bfv = b2[jg], bov = b3[jg];

  __syncthreads();   // staging complete (only barrier in the kernel)

  // ---- preload Wh fragments into registers (64 VGPRs)
  bf16x8 bhf[16];
#pragma unroll
  for (int s = 0; s < 16; ++s)
    bhf[s] = *reinterpret_cast<const bf16x8*>(&Blds[nlo][EDIM + s * 32 + q * 8]);

  const int  myrow = waveid * 16 + lane;   // rows this wave publishes (lane<16)
  const bool hpub  = (lane < 16);

  for (int t = 0; t < T_STEPS; ++t) {
    // ---- issue all h-chunk loads first (longest pole; latency hides under
    //      the emb MFMA block below)
    const u64* hrow = hb + (size_t)(t & 3) * BUF64 + (size_t)mrow * ROW64;
    u64 hva[16], hvb[16];
#pragma unroll
    for (int s = 0; s < 16; ++s) {
      hva[s] = __hip_atomic_load(&hrow[8*s + 2*q],     __ATOMIC_RELAXED, __HIP_MEMORY_SCOPE_AGENT);
      hvb[s] = __hip_atomic_load(&hrow[8*s + 2*q + 1], __ATOMIC_RELAXED, __HIP_MEMORY_SCOPE_AGENT);
    }

    // ---- poison own chunk of buf[(t+2)%4] (everyone has consumed it: my
    //      progress to iter t proves all WGs published h_{t-1}, which they do
    //      only after fully consuming slot (t-2)&3 == (t+2)&3)
    if (hpub)
      __hip_atomic_store(&hb[(size_t)((t + 2) & 3) * BUF64 + (size_t)myrow * ROW64 + w],
                         POISON, __ATOMIC_RELAXED, __HIP_MEMORY_SCOPE_AGENT);

    // ---- emb part (independent of recurrence)
    floatx4 acc0 = {0.f, 0.f, 0.f, 0.f};
    floatx4 acc1 = {0.f, 0.f, 0.f, 0.f};
    const u16* erow = embb + ((size_t)t * BATCH + mrow) * EDIM;
#pragma unroll
    for (int s = 0; s < 16; s += 2) {
      int k0 = s * 32 + q * 8;
      int k1 = (s + 1) * 32 + q * 8;
      bf16x8 a0 = *reinterpret_cast<const bf16x8*>(erow + k0);
      bf16x8 a1 = *reinterpret_cast<const bf16x8*>(erow + k1);
      bf16x8 w0 = *reinterpret_cast<const bf16x8*>(&Blds[nlo][k0]);
      bf16x8 w1 = *reinterpret_cast<const bf16x8*>(&Blds[nlo][k1]);
      acc0 = __builtin_amdgcn_mfma_f32_16x16x32_bf16(a0, w0, acc0, 0, 0, 0);
      acc1 = __builtin_amdgcn_mfma_f32_16x16x32_bf16(a1, w1, acc1, 0, 0, 0);
    }

    // ---- BATCHED poison poll: re-issue ALL stale chunks per round, so each
    //      round costs one L3 round trip total (R1's serial loop cost 16)
    u32 stale = 0xFFFFu;
    for (;;) {
#pragma unroll
      for (int s = 0; s < 16; ++s) {
        if (stale & (1u << s)) {
          if (__all((hva[s] != POISON) && (hvb[s] != POISON)))
            stale &= ~(1u << s);
        }
      }
      if (stale == 0u) break;
#pragma unroll
      for (int s = 0; s < 16; ++s) {
        if (stale & (1u << s)) {
          hva[s] = __hip_atomic_load(&hrow[8*s + 2*q],     __ATOMIC_RELAXED, __HIP_MEMORY_SCOPE_AGENT);
          hvb[s] = __hip_atomic_load(&hrow[8*s + 2*q + 1], __ATOMIC_RELAXED, __HIP_MEMORY_SCOPE_AGENT);
        }
      }
    }

    // ---- h MFMAs with register Wh frags
#pragma unroll
    for (int s = 0; s < 16; ++s) {
      union { u64 qv[2]; bf16x8 v; } ua;
      ua.qv[0] = hva[s]; ua.qv[1] = hvb[s];
      if (s & 1) acc1 = __builtin_amdgcn_mfma_f32_16x16x32_bf16(ua.v, bhf[s], acc1, 0, 0, 0);
      else       acc0 = __builtin_amdgcn_mfma_f32_16x16x32_bf16(ua.v, bhf[s], acc0, 0, 0, 0);
    }

    // ---- stage pre-activations (wave-local rows; in-order DS, no barrier)
#pragma unroll
    for (int r = 0; r < 4; ++r)
      gbuf[waveid * 16 + q * 4 + r][nlo] = acc0[r] + acc1[r];

    // ---- epilogue (reads only own wave's gbuf rows)
    float gv = fast_tanh   (gbuf[eb][ej]      + bgv);
    float iv = fast_sigmoid(gbuf[eb][4 + ej]  + biv);
    float fv = fast_sigmoid(gbuf[eb][8 + ej]  + bfv);
    float ov = fast_sigmoid(gbuf[eb][12 + ej] + bov);
    cst = gv * iv + cst * fv;
    float hv = fast_tanh(cst) * ov;

    hstage[eb][ej] = f2bf(hv);   // wave-local rows

    // ---- publish h slice: one atomic u64 per row (lanes 0..15 of each wave)
    if (hpub) {
      u64 hword = *reinterpret_cast<const u64*>(&hstage[myrow][0]);
      // orders my poison of this slot (issued a full step's work ago, already
      // acked) before the publish; nothing else is outstanding -> ~free
      asm volatile("s_waitcnt vmcnt(0)" ::: "memory");
      __hip_atomic_store(&hb[(size_t)((t + 1) & 3) * BUF64 + (size_t)myrow * ROW64 + w],
                         hword, __ATOMIC_RELAXED, __HIP_MEMORY_SCOPE_AGENT);
    }

    // ---- seq output (after publish so its ack is off the critical path)
    out[((size_t)t * BATCH + eb) * HDIM + jg] = hv;
    if (t == T_STEPS - 1) {
      const size_t seqN = (size_t)T_STEPS * BATCH * HDIM;
      out[seqN + (size_t)eb * HDIM + jg] = hv;
      out[seqN + (size_t)BATCH * HDIM + (size_t)eb * HDIM + jg] = cst;
    }
  }
}

// ---------------------------------------------------------------- launch
extern "C" void kernel_launch(void* const* d_in, const int* in_sizes, int n_in,
                              void* d_out, int out_size, void* d_ws, size_t ws_size,
                              hipStream_t stream) {
  const float* emb = (const float*)d_in[0];
  const float* h0  = (const float*)d_in[1];
  const float* c0  = (const float*)d_in[2];
  const float* Wgx = (const float*)d_in[3];
  const float* Wgh = (const float*)d_in[4];
  const float* bg  = (const float*)d_in[5];
  const float* Wix = (const float*)d_in[6];
  const float* Wih = (const float*)d_in[7];
  const float* bi  = (const float*)d_in[8];
  const float* Wfx = (const float*)d_in[9];
  const float* Wfh = (const float*)d_in[10];
  const float* bf  = (const float*)d_in[11];
  const float* Wox = (const float*)d_in[12];
  const float* Woh = (const float*)d_in[13];
  const float* bo  = (const float*)d_in[14];
  float* out = (float*)d_out;

  char* ws = (char*)d_ws;
  const size_t embb_bytes = (size_t)T_STEPS * BATCH * EDIM * 2;   // 64 MiB
  u16* embb = (u16*)ws;
  u64* hb   = (u64*)(ws + embb_bytes);                            // 128 KiB ring

  lstm_prep<<<4096, 256, 0, stream>>>(emb, embb, h0, hb);
  lstm_rec<<<NW, WG_THREADS, 0, stream>>>(embb, c0,
                                          Wgx, Wgh, bg,
                                          Wix, Wih, bi,
                                          Wfx, Wfh, bf,
                                          Wox, Woh, bo,
                                          hb, out);
}